// Round 1
// baseline (245.559 us; speedup 1.0000x reference)
//
#include <hip/hip_runtime.h>
#include <stdint.h>

// Problem constants
#define NMOL 4096
#define APM 64                 // atoms per molecule
#define NATOMS (NMOL * APM)    // 262144
#define NF 124
#define NT 8
#define ROWV 125               // x_padded row stride in floats

// ws layout (bytes)
#define WS_TOTALS 0            // uint[8]
#define WS_CURSOR 32           // uint[8]
#define WS_DCONST 64           // float[8]
#define WS_TYPEBUF 128         // uchar[NATOMS]
#define WS_LIST 262400         // uint[NATOMS]  (128+262144=262272, padded)

typedef __attribute__((ext_vector_type(8))) short short8;
typedef __attribute__((ext_vector_type(4))) float floatx4;

__device__ __forceinline__ unsigned short f2bf(float f) {
    // round-to-nearest-even fp32 -> bf16
    unsigned u = __builtin_bit_cast(unsigned, f);
    u += 0x7fffu + ((u >> 16) & 1u);
    return (unsigned short)(u >> 16);
}

// ---------------- K0: zero out + totals ----------------
__global__ __launch_bounds__(256) void k_zero(float* out, unsigned* totals) {
    int i = blockIdx.x * 256 + threadIdx.x;
    if (i < NMOL) out[i] = 0.0f;
    if (blockIdx.x == 0 && threadIdx.x < NT) totals[threadIdx.x] = 0u;
}

// ---------------- K1: histogram + type cache ----------------
__global__ __launch_bounds__(256) void k_hist(const float* __restrict__ x,
                                              const float* __restrict__ mask,
                                              unsigned* totals,
                                              unsigned char* typebuf) {
    __shared__ unsigned hist[NT];
    int tid = threadIdx.x;
    if (tid < NT) hist[tid] = 0u;
    __syncthreads();
    int base = blockIdx.x * 1024;
    for (int i = 0; i < 4; ++i) {
        int atom = base + i * 256 + tid;
        float tf = x[(size_t)atom * ROWV];   // type stored at feature 0
        float m  = mask[atom];
        int t = (int)tf;
        unsigned char tb = 0xFF;
        if (m != 0.0f) { tb = (unsigned char)t; atomicAdd(&hist[t], 1u); }
        typebuf[atom] = tb;
    }
    __syncthreads();
    if (tid < NT && hist[tid]) atomicAdd(&totals[tid], hist[tid]);
}

// ---------------- K2: fp32 constants + cursor init ----------------
__global__ __launch_bounds__(128) void k_setup(const float* __restrict__ b1,
                                               const float* __restrict__ W2,
                                               const float* __restrict__ b2,
                                               const float* __restrict__ W3,
                                               const float* __restrict__ b3,
                                               const unsigned* __restrict__ totals,
                                               unsigned* cursor, float* dconst) {
    __shared__ float c[NT];
    int tid = threadIdx.x;           // 128 = 8 types * 16 g
    int t = tid >> 4, g = tid & 15;
    // h2_pre[g] = b2[t][g] + sum_h relu(b1[t][h]) * W2[t][h][g]
    float acc = b2[t * 16 + g];
    for (int h = 0; h < 64; ++h) {
        float h1 = b1[t * 64 + h];
        h1 = h1 > 0.f ? h1 : 0.f;
        acc += h1 * W2[t * 1024 + h * 16 + g];
    }
    float h2 = acc > 0.f ? acc : 0.f;
    float v = h2 * W3[t * 16 + g];
    #pragma unroll
    for (int off = 1; off < 16; off <<= 1) v += __shfl_xor(v, off);
    if (g == 0) c[t] = v + b3[t];
    __syncthreads();
    if (tid == 0) {
        float tot = 0.f;
        for (int i = 0; i < NT; ++i) tot += c[i];
        unsigned run = 0;
        for (int i = 0; i < NT; ++i) {
            dconst[i] = tot - c[i];   // constant added per kept atom of type i
            cursor[i] = run;          // exclusive prefix = segment start
            run += totals[i];
        }
    }
}

// ---------------- K3: counting-sort scatter ----------------
__global__ __launch_bounds__(256) void k_scatter(const unsigned char* __restrict__ typebuf,
                                                 unsigned* cursor, unsigned* list) {
    __shared__ unsigned hist[NT], basep[NT], cur[NT];
    int tid = threadIdx.x;
    if (tid < NT) { hist[tid] = 0u; cur[tid] = 0u; }
    __syncthreads();
    int base = blockIdx.x * 1024;
    unsigned char tb[4];
    for (int i = 0; i < 4; ++i) {
        tb[i] = typebuf[base + i * 256 + tid];
        if (tb[i] != 0xFF) atomicAdd(&hist[tb[i]], 1u);
    }
    __syncthreads();
    if (tid < NT && hist[tid]) basep[tid] = atomicAdd(&cursor[tid], hist[tid]);
    __syncthreads();
    for (int i = 0; i < 4; ++i) {
        if (tb[i] != 0xFF) {
            unsigned p = basep[tb[i]] + atomicAdd(&cur[tb[i]], 1u);
            list[p] = (unsigned)(base + i * 256 + tid);
        }
    }
}

// ---------------- K4: fused gather + 3-layer MLP (bf16 MFMA) ----------------
// Tile: 128 atoms of one type. LDS: A[128][136] bf16 + W[64][136] bf16 + ids[128]
// = 34816 + 17408 + 512 = 52736 B -> 3 blocks/CU.
#define AS 136   // A row stride (bf16): 124 data + pad, 16B-aligned, 2-way bank only
#define HS 72    // h1 row stride (bf16): 64 data + pad

__global__ __launch_bounds__(256, 3) void k_mlp(const float* __restrict__ x,
                                                const float* __restrict__ W1,
                                                const float* __restrict__ b1,
                                                const float* __restrict__ W2,
                                                const float* __restrict__ b2,
                                                const float* __restrict__ W3,
                                                const float* __restrict__ b3,
                                                const unsigned* __restrict__ totals,
                                                const float* __restrict__ dconst,
                                                const unsigned* __restrict__ list,
                                                float* __restrict__ out) {
    __shared__ unsigned short sA[128 * AS];   // feats tile; reused as h1[128][HS]
    __shared__ unsigned short sW[64 * AS];    // W1^T [h][f]; reused as W2^T [g][h]
    __shared__ unsigned sIds[128];

    // ---- locate (type, tile) from totals ----
    unsigned g = blockIdx.x;
    unsigned cnt[NT], start[NT];
    {
        unsigned s = 0;
        for (int i = 0; i < NT; ++i) { cnt[i] = totals[i]; start[i] = s; s += cnt[i]; }
    }
    int t = -1; unsigned tile = 0;
    {
        unsigned tl = 0;
        for (int i = 0; i < NT; ++i) {
            unsigned nt_ = (cnt[i] + 127u) >> 7;
            if (t < 0 && g < tl + nt_) { t = i; tile = g - tl; }
            tl += nt_;
        }
    }
    if (t < 0) return;   // past last tile (uniform per block)

    int valid = (int)cnt[t] - (int)(tile << 7);
    if (valid > 128) valid = 128;
    unsigned rowstart = start[t] + (tile << 7);

    int tid  = threadIdx.x;
    int wv   = tid >> 6;
    int lane = tid & 63;
    int quad = lane >> 4, l15 = lane & 15;

    // ---- gather 128 atom rows -> bf16 LDS (2 threads per row) ----
    {
        int row = tid >> 1, half = tid & 1;
        unsigned short* dst = sA + row * AS + half * 62;
        if (row < valid) {
            unsigned atom = list[rowstart + row];
            if (half == 0) sIds[row] = atom;
            const float* src = x + (size_t)atom * ROWV + 1 + half * 62;
            #pragma unroll
            for (int j = 0; j < 62; j += 2) {
                unsigned pack = (unsigned)f2bf(src[j]) | ((unsigned)f2bf(src[j + 1]) << 16);
                *(unsigned*)(dst + j) = pack;
            }
        } else {
            #pragma unroll
            for (int j = 0; j < 62; j += 2) *(unsigned*)(dst + j) = 0u;
        }
        if (half == 1) {   // zero K pad 124..127
            *(unsigned*)(sA + row * AS + 124) = 0u;
            *(unsigned*)(sA + row * AS + 126) = 0u;
        }
    }

    // ---- stage W1[t] transposed: sW[h][f] ----
    {
        const float* w1g = W1 + (size_t)t * NF * 64;
        for (int i = tid; i < NF * 64; i += 256) {
            int f = i >> 6, h = i & 63;
            sW[h * AS + f] = f2bf(w1g[i]);
        }
        // zero pad f = 124..127
        int h = tid >> 2, f = 124 + (tid & 3);
        if (h < 64) sW[h * AS + f] = 0;
    }

    // b1 per lane per n-tile
    float b1v[4];
    #pragma unroll
    for (int n = 0; n < 4; ++n) b1v[n] = b1[t * 64 + n * 16 + l15];

    __syncthreads();

    // ---- layer 1: [128x128] x [128x64] via 16x16x32 MFMA ----
    floatx4 c1[2][4];
    #pragma unroll
    for (int m = 0; m < 2; ++m)
        #pragma unroll
        for (int n = 0; n < 4; ++n) c1[m][n] = (floatx4)0.f;

    int rowbase = wv * 32;
    #pragma unroll
    for (int ks = 0; ks < 4; ++ks) {
        int ko = ks * 32 + quad * 8;
        short8 a0 = *(const short8*)(sA + (rowbase + l15) * AS + ko);
        short8 a1 = *(const short8*)(sA + (rowbase + 16 + l15) * AS + ko);
        short8 bf[4];
        #pragma unroll
        for (int n = 0; n < 4; ++n)
            bf[n] = *(const short8*)(sW + (n * 16 + l15) * AS + ko);
        #pragma unroll
        for (int n = 0; n < 4; ++n) {
            c1[0][n] = __builtin_amdgcn_mfma_f32_16x16x32_bf16(a0, bf[n], c1[0][n], 0, 0, 0);
            c1[1][n] = __builtin_amdgcn_mfma_f32_16x16x32_bf16(a1, bf[n], c1[1][n], 0, 0, 0);
        }
    }

    __syncthreads();

    // ---- stage W2[t] transposed into sW: sW[g][h] ----
    {
        const float* w2g = W2 + (size_t)t * 64 * 16;
        for (int i = tid; i < 64 * 16; i += 256) {
            int h = i >> 4, gg = i & 15;
            sW[gg * HS + h] = f2bf(w2g[i]);
        }
    }
    // ---- h1 = relu(c1 + b1) -> sA as [row][HS] bf16 ----
    #pragma unroll
    for (int m = 0; m < 2; ++m)
        #pragma unroll
        for (int n = 0; n < 4; ++n) {
            int col = n * 16 + l15;
            #pragma unroll
            for (int r = 0; r < 4; ++r) {
                float v = c1[m][n][r] + b1v[n];
                v = v > 0.f ? v : 0.f;
                sA[(rowbase + m * 16 + quad * 4 + r) * HS + col] = f2bf(v);
            }
        }

    __syncthreads();

    // ---- layer 2: [128x64] x [64x16] ----
    floatx4 c2[2];
    c2[0] = (floatx4)0.f; c2[1] = (floatx4)0.f;
    #pragma unroll
    for (int ks = 0; ks < 2; ++ks) {
        int ko = ks * 32 + quad * 8;
        short8 a0 = *(const short8*)(sA + (rowbase + l15) * HS + ko);
        short8 a1 = *(const short8*)(sA + (rowbase + 16 + l15) * HS + ko);
        short8 bf = *(const short8*)(sW + l15 * HS + ko);
        c2[0] = __builtin_amdgcn_mfma_f32_16x16x32_bf16(a0, bf, c2[0], 0, 0, 0);
        c2[1] = __builtin_amdgcn_mfma_f32_16x16x32_bf16(a1, bf, c2[1], 0, 0, 0);
    }

    // ---- layer 3 + constant + atomic accumulate ----
    float b2v = b2[t * 16 + l15];
    float w3v = W3[t * 16 + l15];
    float tail = b3[t] + dconst[t];
    #pragma unroll
    for (int m = 0; m < 2; ++m) {
        float h2v[4];
        #pragma unroll
        for (int r = 0; r < 4; ++r) {
            float v = c2[m][r] + b2v;
            v = v > 0.f ? v : 0.f;
            h2v[r] = v * w3v;
        }
        #pragma unroll
        for (int off = 1; off < 16; off <<= 1)
            #pragma unroll
            for (int r = 0; r < 4; ++r) h2v[r] += __shfl_xor(h2v[r], off);
        if (l15 == 0) {
            #pragma unroll
            for (int r = 0; r < 4; ++r) {
                int trow = rowbase + m * 16 + quad * 4 + r;
                if (trow < valid) {
                    unsigned atom = sIds[trow];
                    atomicAdd(&out[atom >> 6], h2v[r] + tail);
                }
            }
        }
    }
}

extern "C" void kernel_launch(void* const* d_in, const int* in_sizes, int n_in,
                              void* d_out, int out_size, void* d_ws, size_t ws_size,
                              hipStream_t stream) {
    const float* x    = (const float*)d_in[0];
    const float* mask = (const float*)d_in[1];
    const float* W1   = (const float*)d_in[2];
    const float* b1   = (const float*)d_in[3];
    const float* W2   = (const float*)d_in[4];
    const float* b2   = (const float*)d_in[5];
    const float* W3   = (const float*)d_in[6];
    const float* b3   = (const float*)d_in[7];
    float* out = (float*)d_out;

    char* ws = (char*)d_ws;
    unsigned*       totals  = (unsigned*)(ws + WS_TOTALS);
    unsigned*       cursor  = (unsigned*)(ws + WS_CURSOR);
    float*          dconst  = (float*)(ws + WS_DCONST);
    unsigned char*  typebuf = (unsigned char*)(ws + WS_TYPEBUF);
    unsigned*       list    = (unsigned*)(ws + WS_LIST);

    k_zero<<<16, 256, 0, stream>>>(out, totals);
    k_hist<<<NATOMS / 1024, 256, 0, stream>>>(x, mask, totals, typebuf);
    k_setup<<<1, 128, 0, stream>>>(b1, W2, b2, W3, b3, totals, cursor, dconst);
    k_scatter<<<NATOMS / 1024, 256, 0, stream>>>(typebuf, cursor, list);
    // worst case sum of per-type tiles: 262144/128 + 7 = 2055
    k_mlp<<<2055, 256, 0, stream>>>(x, W1, b1, W2, b2, W3, b3,
                                    totals, dconst, list, out);
}